// Round 16
// baseline (71.844 us; speedup 1.0000x reference)
//
#include <hip/hip_runtime.h>
#include <hip/hip_bf16.h>

#define TOKENS 8192
#define D_IN   256
#define HDIM   1024
#define ODIM   768
#define KPACK  704    // 640 statically-valid cols + bias chunk + pad
#define NCHUNK 88     // KPACK/8

typedef short bf16x8 __attribute__((ext_vector_type(8)));
typedef float f32x4  __attribute__((ext_vector_type(4)));

static __device__ __forceinline__ ushort f2b(float f) {
    union { __hip_bfloat16 b; ushort u; } cv;
    cv.b = __float2bfloat16(f);
    return cv.u;
}
static __device__ __forceinline__ float b2f(ushort u) {
    union { ushort u; __hip_bfloat16 b; } cv;
    cv.u = u;
    return __bfloat162float(cv.b);
}

// packed chunk index (0..79) -> (expert, source col d0); static masks:
// e0: cols [0,32)u[128,160) = 8 chunks; e1: 16; e2: 24; e3: 32 chunks
static __device__ __forceinline__ void chunk_map(int c8, int& e, int& d0) {
    int cc;
    if (c8 < 8)       { e = 0; cc = c8; }
    else if (c8 < 24) { e = 1; cc = c8 - 8; }
    else if (c8 < 48) { e = 2; cc = c8 - 24; }
    else              { e = 3; cc = c8 - 48; }
    int half = 4 * (e + 1);
    d0 = (cc < half) ? cc * 8 : 128 + (cc - half) * 8;
}

// direct global->LDS DMA, 16B/lane; LDS dest = wave-uniform base + lane*16
static __device__ __forceinline__ void stage16(const ushort* g, ushort* l) {
    __builtin_amdgcn_global_load_lds(
        (const __attribute__((address_space(1))) void*)g,
        (__attribute__((address_space(3))) void*)l, 16, 0, 0);
}

// tanh-form GELU (max dev from exact erf-GELU ~3e-4)
static __device__ __forceinline__ float gelu_f(float v) {
    float y = 0.7978845608f * v * (1.f + 0.044715f * v * v);
    return v - v / (__expf(2.f * y) + 1.f);
}

// ---- K0: fused packing: A'' (route inline) + B'' + W_out -------------------
#define A_ITEMS  (TOKENS * NCHUNK)            // 720896
#define B_ITEMS  (1792 * NCHUNK)              // 157696
#define W_ITEMS  (768 * 128)                  // 98304   -> total 976896 = 3816*256
__global__ __launch_bounds__(256) void k_pack(
    const float* __restrict__ ew, const int* __restrict__ ei,
    const float* __restrict__ xf,
    const float* __restrict__ Whid, const float* __restrict__ bhid,
    const float* __restrict__ Wres, const float* __restrict__ bres,
    const float* __restrict__ Wout,
    ushort* __restrict__ Ap, ushort* __restrict__ Bp, ushort* __restrict__ Wb) {
    int gid = blockIdx.x * 256 + threadIdx.x;
    if (gid < A_ITEMS) {
        int n  = gid / NCHUNK;
        int c8 = gid - n * NCHUNK;
        int   i0 = ei[2 * n], i1 = ei[2 * n + 1];
        float w0 = ew[2 * n], w1 = ew[2 * n + 1];
        bool v0 = (unsigned)i0 < 4u, v1 = (unsigned)i1 < 4u;
        float rs = (v0 ? w0 : 0.f) + (v1 ? w1 : 0.f);
        if (rs == 0.f) rs = 1.f;
        float o0 = v0 ? w0 / rs : 0.f;
        float o1 = v1 ? w1 / rs : 0.f;
        ushort o[8] __attribute__((aligned(16))) = {0, 0, 0, 0, 0, 0, 0, 0};
        if (c8 < 80) {
            int e, d0;
            chunk_map(c8, e, d0);
            float w = ((v0 && i0 == e) ? o0 : 0.f) + ((v1 && i1 == e) ? o1 : 0.f);
            if (w != 0.f) {
                const float* s = xf + ((size_t)e * TOKENS + n) * D_IN + d0;
#pragma unroll
                for (int j = 0; j < 8; ++j) {
                    float v = s[j];
                    if (!(v == v)) v = 0.f;   // nan_to_num
                    o[j] = f2b(w * v);
                }
            }
        } else if (c8 == 80) {
#pragma unroll
            for (int j = 0; j < 4; ++j) {
                float m = ((v0 && i0 == j) ? o0 : 0.f) + ((v1 && i1 == j) ? o1 : 0.f);
                o[j] = f2b(m);
            }
        }
        *(uint4*)(Ap + (size_t)n * KPACK + c8 * 8) = *(const uint4*)o;
    } else if (gid < A_ITEMS + B_ITEMS) {
        int g2 = gid - A_ITEMS;
        int o_ = g2 / NCHUNK;
        int c8 = g2 - o_ * NCHUNK;
        ushort v[8] __attribute__((aligned(16))) = {0, 0, 0, 0, 0, 0, 0, 0};
        if (c8 < 80) {
            int e, d0;
            chunk_map(c8, e, d0);
            const float* s = (o_ < HDIM)
                ? Whid + ((size_t)e * HDIM + o_) * D_IN + d0
                : Wres + ((size_t)e * ODIM + (o_ - HDIM)) * D_IN + d0;
#pragma unroll
            for (int j = 0; j < 8; ++j) v[j] = f2b(s[j]);
        } else if (c8 == 80) {
#pragma unroll
            for (int j = 0; j < 4; ++j) {
                float b = (o_ < HDIM) ? bhid[j * HDIM + o_] : bres[j * ODIM + (o_ - HDIM)];
                v[j] = f2b(b);
            }
        }
        *(uint4*)(Bp + (size_t)o_ * KPACK + c8 * 8) = *(const uint4*)v;
    } else {
        int g3 = gid - A_ITEMS - B_ITEMS;
        const float* s = Wout + (size_t)g3 * 8;
        ushort v[8] __attribute__((aligned(16)));
#pragma unroll
        for (int j = 0; j < 8; ++j) v[j] = f2b(s[j]);
        *(uint4*)(Wb + (size_t)g3 * 8) = *(const uint4*)v;
    }
}

// ---- GEMM1: 128^2 tile, BK=32, 4 blocks/CU, R12-ordering pipeline ----------
// LDS = 2 x (4KB A + 4KB B) x2 = 32KB -> 4 blocks/CU at 16 waves. 22 K-tiles.
// Rows are 64B (4 x 16B slots); swizzle: LDS[row][s] = glob[row][s^((row>>1)&3)].
// 4 stage-calls/tile -> vmcnt(4) steady state (tile t complete, t+1 flying).
__global__ __launch_bounds__(256, 4) void k_gemm1(
    const ushort* __restrict__ A, const ushort* __restrict__ B,
    ushort* __restrict__ hidB, ushort* __restrict__ resb) {
    __shared__ __align__(16) ushort As[2][128 * 32];   // 8KB each
    __shared__ __align__(16) ushort Bs[2][128 * 32];
    const int tid = threadIdx.x;
    const int lane = tid & 63, w = tid >> 6;
    const int wr = w >> 1, wc = w & 1;
    const int r = lane & 15, g = lane >> 4;
    const int sx2 = (r >> 1) & 3;

    // XCD-bijective swizzle: 896 blocks = 8 x 112; consecutive widx share bm
    int bid  = blockIdx.x;
    int widx = (bid & 7) * 112 + (bid >> 3);
    int bm = widx / 14, bn = widx - bm * 14;

    // staging: call = 256 thr x 16B = 4KB = 64 rows x 64B; srow=tid>>2, slot=tid&3
    const int srow = tid >> 2;                  // 0..63
    const int gc   = (tid & 3) ^ ((srow >> 1) & 3);
    const ushort* Ag = A + (size_t)(bm * 128 + srow) * KPACK + gc * 8;
    const ushort* Bg = B + (size_t)(bn * 128 + srow) * KPACK + gc * 8;
    const int ldst = (w * 16) * 32;             // wave covers 16 rows/call

#define G1_STAGE(p, kt) do {                                            \
    _Pragma("unroll")                                                   \
    for (int i_ = 0; i_ < 2; ++i_) {                                    \
        stage16(Ag + (size_t)(i_ * 64) * KPACK + (kt), &As[p][ldst + i_ * 64 * 32]); \
        stage16(Bg + (size_t)(i_ * 64) * KPACK + (kt), &Bs[p][ldst + i_ * 64 * 32]); \
    } } while (0)

    G1_STAGE(0, 0);
    G1_STAGE(1, 32);

    f32x4 acc[4][4] = {};
    const int cA = (wr * 64 + r) * 32;
    const int cB = (wc * 64 + r) * 32;
    const int cs = ((g ^ sx2) * 8);

    int cur = 0;
#pragma unroll
    for (int t = 0; t < 22; ++t) {
        if (t < 21) asm volatile("s_waitcnt vmcnt(4)" ::: "memory");
        else        asm volatile("s_waitcnt vmcnt(0)" ::: "memory");
        __builtin_amdgcn_s_barrier();
        const ushort* Ab = As[cur];
        const ushort* Bb = Bs[cur];
        bf16x8 af[4], bf_[4];
#pragma unroll
        for (int j = 0; j < 4; ++j) bf_[j] = *(const bf16x8*)&Bb[cB + j * 16 * 32 + cs];
#pragma unroll
        for (int i = 0; i < 4; ++i) af[i] = *(const bf16x8*)&Ab[cA + i * 16 * 32 + cs];
        asm volatile("s_waitcnt lgkmcnt(0)" ::: "memory");
        __builtin_amdgcn_sched_barrier(0);
        __builtin_amdgcn_s_barrier();
        if (t + 2 < 22) G1_STAGE(cur, (t + 2) * 32);   // early issue under MFMA
        __builtin_amdgcn_s_setprio(1);
#pragma unroll
        for (int i = 0; i < 4; ++i)
#pragma unroll
            for (int j = 0; j < 4; ++j)
                acc[i][j] = __builtin_amdgcn_mfma_f32_16x16x32_bf16(
                    af[i], bf_[j], acc[i][j], 0, 0, 0);
        __builtin_amdgcn_s_setprio(0);
        cur ^= 1;
    }
#undef G1_STAGE

    if (bn < 8) {   // hid block: GELU -> bf16
#pragma unroll
        for (int fi = 0; fi < 4; ++fi) {
#pragma unroll
            for (int j = 0; j < 4; ++j) {
                int col = bn * 128 + wc * 64 + j * 16 + r;
#pragma unroll
                for (int qq = 0; qq < 4; ++qq) {
                    int row = bm * 128 + wr * 64 + fi * 16 + g * 4 + qq;
                    hidB[(size_t)row * HDIM + col] = f2b(gelu_f(acc[fi][j][qq]));
                }
            }
        }
    } else {        // res block
#pragma unroll
        for (int fi = 0; fi < 4; ++fi) {
#pragma unroll
            for (int j = 0; j < 4; ++j) {
                int col = (bn - 8) * 128 + wc * 64 + j * 16 + r;
#pragma unroll
                for (int qq = 0; qq < 4; ++qq) {
                    int row = bm * 128 + wr * 64 + fi * 16 + g * 4 + qq;
                    resb[(size_t)row * ODIM + col] = f2b(acc[fi][j][qq]);
                }
            }
        }
    }
}

// ---- GEMM2: exact R12 structure (BK=64, 2 blocks/CU, early staging) --------
__global__ __launch_bounds__(256, 2) void k_gemm2(
    const ushort* __restrict__ A, const ushort* __restrict__ B,
    const float* __restrict__ bout, const ushort* __restrict__ resb,
    ushort* __restrict__ outb) {
    __shared__ __align__(16) ushort As[2][128 * 64];
    __shared__ __align__(16) ushort Bs[2][128 * 64];
    const int tid = threadIdx.x;
    const int lane = tid & 63, w = tid >> 6;
    const int wr = w >> 1, wc = w & 1;
    const int r = lane & 15, g = lane >> 4;
    const int bm = blockIdx.x, bn = blockIdx.y;

    const int srow = tid >> 3;
    const int gc   = (tid & 7) ^ (srow & 7);
    const ushort* Ag = A + (size_t)(bm * 128 + srow) * HDIM + gc * 8;
    const ushort* Bg = B + (size_t)(bn * 128 + srow) * HDIM + gc * 8;
    const int ldst = (w * 8) * 64;

#define G2_STAGE(p, kt) do {                                            \
    _Pragma("unroll")                                                   \
    for (int i_ = 0; i_ < 4; ++i_) {                                    \
        stage16(Ag + (size_t)(i_ * 32) * HDIM + (kt), &As[p][ldst + i_ * 32 * 64]); \
        stage16(Bg + (size_t)(i_ * 32) * HDIM + (kt), &Bs[p][ldst + i_ * 32 * 64]); \
    } } while (0)

    G2_STAGE(0, 0);
    G2_STAGE(1, 64);

    f32x4 acc[4][4] = {};
    const int cA = (wr * 64 + r) * 64;
    const int cB = (wc * 64 + r) * 64;
    const int sx = r & 7;
    const int cs0 = ((0 * 4 + g) ^ sx) * 8;
    const int cs1 = ((1 * 4 + g) ^ sx) * 8;

    int cur = 0;
#pragma unroll
    for (int t = 0; t < 16; ++t) {
        if (t < 15) asm volatile("s_waitcnt vmcnt(8)" ::: "memory");
        else        asm volatile("s_waitcnt vmcnt(0)" ::: "memory");
        __builtin_amdgcn_s_barrier();
        const ushort* Ab = As[cur];
        const ushort* Bb = Bs[cur];
        bf16x8 a0[4], b0[4], a1[4], b1[4];
#pragma unroll
        for (int j = 0; j < 4; ++j) {
            b0[j] = *(const bf16x8*)&Bb[cB + j * 16 * 64 + cs0];
            b1[j] = *(const bf16x8*)&Bb[cB + j * 16 * 64 + cs1];
        }
#pragma unroll
        for (int i = 0; i < 4; ++i) {
            a0[i] = *(const bf16x8*)&Ab[cA + i * 16 * 64 + cs0];
            a1[i] = *(const bf16x8*)&Ab[cA + i * 16 * 64 + cs1];
        }
        asm volatile("s_waitcnt lgkmcnt(0)" ::: "memory");
        __builtin_amdgcn_sched_barrier(0);
        __builtin_amdgcn_s_barrier();
        if (t + 2 < 16) G2_STAGE(cur, (t + 2) * 64);   // early issue under MFMA
        __builtin_amdgcn_s_setprio(1);
#pragma unroll
        for (int i = 0; i < 4; ++i)
#pragma unroll
            for (int j = 0; j < 4; ++j)
                acc[i][j] = __builtin_amdgcn_mfma_f32_16x16x32_bf16(
                    a0[i], b0[j], acc[i][j], 0, 0, 0);
#pragma unroll
        for (int i = 0; i < 4; ++i)
#pragma unroll
            for (int j = 0; j < 4; ++j)
                acc[i][j] = __builtin_amdgcn_mfma_f32_16x16x32_bf16(
                    a1[i], b1[j], acc[i][j], 0, 0, 0);
        __builtin_amdgcn_s_setprio(0);
        cur ^= 1;
    }
#undef G2_STAGE

#pragma unroll
    for (int fi = 0; fi < 4; ++fi) {
#pragma unroll
        for (int j = 0; j < 4; ++j) {
            int col = bn * 128 + wc * 64 + j * 16 + r;
#pragma unroll
            for (int qq = 0; qq < 4; ++qq) {
                int row = bm * 128 + wr * 64 + fi * 16 + g * 4 + qq;
                size_t idx = (size_t)row * ODIM + col;
                float v = acc[fi][j][qq] + bout[col] + b2f(resb[idx]);
                outb[idx] = f2b(v);
            }
        }
    }
}

// ---- RMS norm row-wise (bf16 in, f32 out) ----------------------------------
__global__ __launch_bounds__(256) void k_rms(
    const ushort* __restrict__ outb, const float* __restrict__ lnw,
    float* __restrict__ out) {
    int row = blockIdx.x, t = threadIdx.x;
    const ushort* p = outb + (size_t)row * ODIM;
    float v0 = b2f(p[t]), v1 = b2f(p[t + 256]), v2 = b2f(p[t + 512]);
    float s = v0 * v0 + v1 * v1 + v2 * v2;
#pragma unroll
    for (int off = 32; off > 0; off >>= 1) s += __shfl_down(s, off, 64);
    __shared__ float ws4[4];
    if ((t & 63) == 0) ws4[t >> 6] = s;
    __syncthreads();
    float tot = ws4[0] + ws4[1] + ws4[2] + ws4[3];
    float sc = rsqrtf(tot * (1.f / 768.f) + 1e-6f);
    out[(size_t)row * ODIM + t]       = lnw[t]       * v0 * sc;
    out[(size_t)row * ODIM + t + 256] = lnw[t + 256] * v1 * sc;
    out[(size_t)row * ODIM + t + 512] = lnw[t + 512] * v2 * sc;
}

extern "C" void kernel_launch(void* const* d_in, const int* in_sizes, int n_in,
                              void* d_out, int out_size, void* d_ws, size_t ws_size,
                              hipStream_t stream) {
    const float* ew   = (const float*)d_in[2];
    const int*   ei   = (const int*)d_in[3];
    const float* xf   = (const float*)d_in[4];
    const float* Whid = (const float*)d_in[5];
    const float* bhid = (const float*)d_in[6];
    const float* Wout = (const float*)d_in[7];
    const float* bout = (const float*)d_in[8];
    const float* Wres = (const float*)d_in[9];
    const float* bres = (const float*)d_in[10];
    const float* lnw  = (const float*)d_in[11];

    char* ws = (char*)d_ws;
    ushort* Ap   = (ushort*)(ws);                    // 8192*704*2 = 11534336
    ushort* Bp   = (ushort*)(ws + 11534336);         // 1792*704*2 = 2523136
    ushort* Wb   = (ushort*)(ws + 14057472);         // 768*1024*2 = 1572864
    ushort* hidB = (ushort*)(ws + 15630336);         // 8192*1024*2 = 16777216
    ushort* resb = (ushort*)(ws + 32407552);         // 8192*768*2  = 12582912
    ushort* outb = (ushort*)(ws + 44990464);         // 8192*768*2  = 12582912

    k_pack<<<3816, 256, 0, stream>>>(ew, ei, xf, Whid, bhid, Wres, bres, Wout,
                                     Ap, Bp, Wb);
    k_gemm1<<<896, 256, 0, stream>>>(Ap, Bp, hidB, resb);
    k_gemm2<<<dim3(64, 6), 256, 0, stream>>>(hidB, Wb, bout, resb, outb);
    k_rms<<<8192, 256, 0, stream>>>(outb, lnw, (float*)d_out);
}

// Round 17
// 67.461 us; speedup vs baseline: 1.0650x; 1.0650x over previous
//
#include <hip/hip_runtime.h>
#include <hip/hip_bf16.h>

#define TOKENS 8192
#define D_IN   256
#define HDIM   1024
#define ODIM   768
#define KPACK  704    // 640 statically-valid cols + bias chunk + pad -> 11 x BK=64
#define NCHUNK 88     // KPACK/8

typedef short bf16x8 __attribute__((ext_vector_type(8)));
typedef float f32x4  __attribute__((ext_vector_type(4)));

static __device__ __forceinline__ ushort f2b(float f) {
    union { __hip_bfloat16 b; ushort u; } cv;
    cv.b = __float2bfloat16(f);
    return cv.u;
}
static __device__ __forceinline__ float b2f(ushort u) {
    union { ushort u; __hip_bfloat16 b; } cv;
    cv.u = u;
    return __bfloat162float(cv.b);
}

// packed chunk index (0..79) -> (expert, source col d0); static masks:
// e0: cols [0,32)u[128,160) = 8 chunks; e1: 16; e2: 24; e3: 32 chunks
static __device__ __forceinline__ void chunk_map(int c8, int& e, int& d0) {
    int cc;
    if (c8 < 8)       { e = 0; cc = c8; }
    else if (c8 < 24) { e = 1; cc = c8 - 8; }
    else if (c8 < 48) { e = 2; cc = c8 - 24; }
    else              { e = 3; cc = c8 - 48; }
    int half = 4 * (e + 1);
    d0 = (cc < half) ? cc * 8 : 128 + (cc - half) * 8;
}

// direct global->LDS DMA, 16B/lane; LDS dest = wave-uniform base + lane*16
static __device__ __forceinline__ void stage16(const ushort* g, ushort* l) {
    __builtin_amdgcn_global_load_lds(
        (const __attribute__((address_space(1))) void*)g,
        (__attribute__((address_space(3))) void*)l, 16, 0, 0);
}

// tanh-form GELU (max dev from exact erf-GELU ~3e-4)
static __device__ __forceinline__ float gelu_f(float v) {
    float y = 0.7978845608f * v * (1.f + 0.044715f * v * v);
    return v - v / (__expf(2.f * y) + 1.f);
}

// ---- K0: fused packing: A'' (route inline) + B'' + W_out -------------------
#define A_ITEMS  (TOKENS * NCHUNK)            // 720896
#define B_ITEMS  (1792 * NCHUNK)              // 157696
#define W_ITEMS  (768 * 128)                  // 98304   -> total 976896 = 3816*256
__global__ __launch_bounds__(256) void k_pack(
    const float* __restrict__ ew, const int* __restrict__ ei,
    const float* __restrict__ xf,
    const float* __restrict__ Whid, const float* __restrict__ bhid,
    const float* __restrict__ Wres, const float* __restrict__ bres,
    const float* __restrict__ Wout,
    ushort* __restrict__ Ap, ushort* __restrict__ Bp, ushort* __restrict__ Wb) {
    int gid = blockIdx.x * 256 + threadIdx.x;
    if (gid < A_ITEMS) {
        int n  = gid / NCHUNK;
        int c8 = gid - n * NCHUNK;
        int   i0 = ei[2 * n], i1 = ei[2 * n + 1];
        float w0 = ew[2 * n], w1 = ew[2 * n + 1];
        bool v0 = (unsigned)i0 < 4u, v1 = (unsigned)i1 < 4u;
        float rs = (v0 ? w0 : 0.f) + (v1 ? w1 : 0.f);
        if (rs == 0.f) rs = 1.f;
        float o0 = v0 ? w0 / rs : 0.f;
        float o1 = v1 ? w1 / rs : 0.f;
        ushort o[8] __attribute__((aligned(16))) = {0, 0, 0, 0, 0, 0, 0, 0};
        if (c8 < 80) {
            int e, d0;
            chunk_map(c8, e, d0);
            float w = ((v0 && i0 == e) ? o0 : 0.f) + ((v1 && i1 == e) ? o1 : 0.f);
            if (w != 0.f) {
                const float* s = xf + ((size_t)e * TOKENS + n) * D_IN + d0;
#pragma unroll
                for (int j = 0; j < 8; ++j) {
                    float v = s[j];
                    if (!(v == v)) v = 0.f;   // nan_to_num
                    o[j] = f2b(w * v);
                }
            }
        } else if (c8 == 80) {
#pragma unroll
            for (int j = 0; j < 4; ++j) {
                float m = ((v0 && i0 == j) ? o0 : 0.f) + ((v1 && i1 == j) ? o1 : 0.f);
                o[j] = f2b(m);
            }
        }
        *(uint4*)(Ap + (size_t)n * KPACK + c8 * 8) = *(const uint4*)o;
    } else if (gid < A_ITEMS + B_ITEMS) {
        int g2 = gid - A_ITEMS;
        int o_ = g2 / NCHUNK;
        int c8 = g2 - o_ * NCHUNK;
        ushort v[8] __attribute__((aligned(16))) = {0, 0, 0, 0, 0, 0, 0, 0};
        if (c8 < 80) {
            int e, d0;
            chunk_map(c8, e, d0);
            const float* s = (o_ < HDIM)
                ? Whid + ((size_t)e * HDIM + o_) * D_IN + d0
                : Wres + ((size_t)e * ODIM + (o_ - HDIM)) * D_IN + d0;
#pragma unroll
            for (int j = 0; j < 8; ++j) v[j] = f2b(s[j]);
        } else if (c8 == 80) {
#pragma unroll
            for (int j = 0; j < 4; ++j) {
                float b = (o_ < HDIM) ? bhid[j * HDIM + o_] : bres[j * ODIM + (o_ - HDIM)];
                v[j] = f2b(b);
            }
        }
        *(uint4*)(Bp + (size_t)o_ * KPACK + c8 * 8) = *(const uint4*)v;
    } else {
        int g3 = gid - A_ITEMS - B_ITEMS;
        const float* s = Wout + (size_t)g3 * 8;
        ushort v[8] __attribute__((aligned(16)));
#pragma unroll
        for (int j = 0; j < 8; ++j) v[j] = f2b(s[j]);
        *(uint4*)(Wb + (size_t)g3 * 8) = *(const uint4*)v;
    }
}

// ---- GEMM1: exact R12 structure (128^2, BK=64, 2 blocks/CU, early staging) -
__global__ __launch_bounds__(256, 2) void k_gemm1(
    const ushort* __restrict__ A, const ushort* __restrict__ B,
    ushort* __restrict__ hidB, ushort* __restrict__ resb) {
    __shared__ __align__(16) ushort As[2][128 * 64];
    __shared__ __align__(16) ushort Bs[2][128 * 64];
    const int tid = threadIdx.x;
    const int lane = tid & 63, w = tid >> 6;
    const int wr = w >> 1, wc = w & 1;
    const int r = lane & 15, g = lane >> 4;
    const int sx = r & 7;

    // XCD-bijective swizzle: 896 blocks = 8 x 112; consecutive widx share bm
    int bid  = blockIdx.x;
    int widx = (bid & 7) * 112 + (bid >> 3);
    int bm = widx / 14, bn = widx - bm * 14;

    const int srow = tid >> 3;                  // 0..31
    const int gc   = (tid & 7) ^ (srow & 7);
    const ushort* Ag = A + (size_t)(bm * 128 + srow) * KPACK + gc * 8;
    const ushort* Bg = B + (size_t)(bn * 128 + srow) * KPACK + gc * 8;
    const int ldst = (w * 8) * 64;

#define G1_STAGE(p, kt) do {                                            \
    _Pragma("unroll")                                                   \
    for (int i_ = 0; i_ < 4; ++i_) {                                    \
        stage16(Ag + (size_t)(i_ * 32) * KPACK + (kt), &As[p][ldst + i_ * 32 * 64]); \
        stage16(Bg + (size_t)(i_ * 32) * KPACK + (kt), &Bs[p][ldst + i_ * 32 * 64]); \
    } } while (0)

    G1_STAGE(0, 0);
    G1_STAGE(1, 64);

    f32x4 acc[4][4] = {};
    const int cA = (wr * 64 + r) * 64;
    const int cB = (wc * 64 + r) * 64;
    const int cs0 = ((0 * 4 + g) ^ sx) * 8;
    const int cs1 = ((1 * 4 + g) ^ sx) * 8;

    int cur = 0;
#pragma unroll
    for (int t = 0; t < 11; ++t) {
        if (t < 10) asm volatile("s_waitcnt vmcnt(8)" ::: "memory");
        else        asm volatile("s_waitcnt vmcnt(0)" ::: "memory");
        __builtin_amdgcn_s_barrier();
        const ushort* Ab = As[cur];
        const ushort* Bb = Bs[cur];
        bf16x8 a0[4], b0[4], a1[4], b1[4];
#pragma unroll
        for (int j = 0; j < 4; ++j) {
            b0[j] = *(const bf16x8*)&Bb[cB + j * 16 * 64 + cs0];
            b1[j] = *(const bf16x8*)&Bb[cB + j * 16 * 64 + cs1];
        }
#pragma unroll
        for (int i = 0; i < 4; ++i) {
            a0[i] = *(const bf16x8*)&Ab[cA + i * 16 * 64 + cs0];
            a1[i] = *(const bf16x8*)&Ab[cA + i * 16 * 64 + cs1];
        }
        asm volatile("s_waitcnt lgkmcnt(0)" ::: "memory");
        __builtin_amdgcn_sched_barrier(0);
        __builtin_amdgcn_s_barrier();
        if (t + 2 < 11) G1_STAGE(cur, (t + 2) * 64);   // early issue under MFMA
        __builtin_amdgcn_s_setprio(1);
#pragma unroll
        for (int i = 0; i < 4; ++i)
#pragma unroll
            for (int j = 0; j < 4; ++j)
                acc[i][j] = __builtin_amdgcn_mfma_f32_16x16x32_bf16(
                    a0[i], b0[j], acc[i][j], 0, 0, 0);
#pragma unroll
        for (int i = 0; i < 4; ++i)
#pragma unroll
            for (int j = 0; j < 4; ++j)
                acc[i][j] = __builtin_amdgcn_mfma_f32_16x16x32_bf16(
                    a1[i], b1[j], acc[i][j], 0, 0, 0);
        __builtin_amdgcn_s_setprio(0);
        cur ^= 1;
    }
#undef G1_STAGE

    if (bn < 8) {   // hid block: GELU -> bf16
#pragma unroll
        for (int fi = 0; fi < 4; ++fi) {
#pragma unroll
            for (int j = 0; j < 4; ++j) {
                int col = bn * 128 + wc * 64 + j * 16 + r;
#pragma unroll
                for (int qq = 0; qq < 4; ++qq) {
                    int row = bm * 128 + wr * 64 + fi * 16 + g * 4 + qq;
                    hidB[(size_t)row * HDIM + col] = f2b(gelu_f(acc[fi][j][qq]));
                }
            }
        }
    } else {        // res block
#pragma unroll
        for (int fi = 0; fi < 4; ++fi) {
#pragma unroll
            for (int j = 0; j < 4; ++j) {
                int col = (bn - 8) * 128 + wc * 64 + j * 16 + r;
#pragma unroll
                for (int qq = 0; qq < 4; ++qq) {
                    int row = bm * 128 + wr * 64 + fi * 16 + g * 4 + qq;
                    resb[(size_t)row * ODIM + col] = f2b(acc[fi][j][qq]);
                }
            }
        }
    }
}

// ---- GEMM2: R12 loop + XCD-chunked bm-major grid (384 = 8 XCD x 48) --------
// Each XCD owns 8 consecutive bm panels -> its hidB slice (2MB) fits the 4MB
// per-XCD L2; Wb (1.5MB) is hot everywhere. A-panel reads become L2 hits.
__global__ __launch_bounds__(256, 2) void k_gemm2(
    const ushort* __restrict__ A, const ushort* __restrict__ B,
    const float* __restrict__ bout, const ushort* __restrict__ resb,
    ushort* __restrict__ outb) {
    __shared__ __align__(16) ushort As[2][128 * 64];
    __shared__ __align__(16) ushort Bs[2][128 * 64];
    const int tid = threadIdx.x;
    const int lane = tid & 63, w = tid >> 6;
    const int wr = w >> 1, wc = w & 1;
    const int r = lane & 15, g = lane >> 4;

    // bijective XCD swizzle: widx = xcd*48 + j; bm-major (bn fastest)
    int bid  = blockIdx.x;
    int widx = (bid & 7) * 48 + (bid >> 3);
    int bm = widx / 6, bn = widx - bm * 6;

    const int srow = tid >> 3;
    const int gc   = (tid & 7) ^ (srow & 7);
    const ushort* Ag = A + (size_t)(bm * 128 + srow) * HDIM + gc * 8;
    const ushort* Bg = B + (size_t)(bn * 128 + srow) * HDIM + gc * 8;
    const int ldst = (w * 8) * 64;

#define G2_STAGE(p, kt) do {                                            \
    _Pragma("unroll")                                                   \
    for (int i_ = 0; i_ < 4; ++i_) {                                    \
        stage16(Ag + (size_t)(i_ * 32) * HDIM + (kt), &As[p][ldst + i_ * 32 * 64]); \
        stage16(Bg + (size_t)(i_ * 32) * HDIM + (kt), &Bs[p][ldst + i_ * 32 * 64]); \
    } } while (0)

    G2_STAGE(0, 0);
    G2_STAGE(1, 64);

    f32x4 acc[4][4] = {};
    const int cA = (wr * 64 + r) * 64;
    const int cB = (wc * 64 + r) * 64;
    const int sx = r & 7;
    const int cs0 = ((0 * 4 + g) ^ sx) * 8;
    const int cs1 = ((1 * 4 + g) ^ sx) * 8;

    int cur = 0;
#pragma unroll
    for (int t = 0; t < 16; ++t) {
        if (t < 15) asm volatile("s_waitcnt vmcnt(8)" ::: "memory");
        else        asm volatile("s_waitcnt vmcnt(0)" ::: "memory");
        __builtin_amdgcn_s_barrier();
        const ushort* Ab = As[cur];
        const ushort* Bb = Bs[cur];
        bf16x8 a0[4], b0[4], a1[4], b1[4];
#pragma unroll
        for (int j = 0; j < 4; ++j) {
            b0[j] = *(const bf16x8*)&Bb[cB + j * 16 * 64 + cs0];
            b1[j] = *(const bf16x8*)&Bb[cB + j * 16 * 64 + cs1];
        }
#pragma unroll
        for (int i = 0; i < 4; ++i) {
            a0[i] = *(const bf16x8*)&Ab[cA + i * 16 * 64 + cs0];
            a1[i] = *(const bf16x8*)&Ab[cA + i * 16 * 64 + cs1];
        }
        asm volatile("s_waitcnt lgkmcnt(0)" ::: "memory");
        __builtin_amdgcn_sched_barrier(0);
        __builtin_amdgcn_s_barrier();
        if (t + 2 < 16) G2_STAGE(cur, (t + 2) * 64);   // early issue under MFMA
        __builtin_amdgcn_s_setprio(1);
#pragma unroll
        for (int i = 0; i < 4; ++i)
#pragma unroll
            for (int j = 0; j < 4; ++j)
                acc[i][j] = __builtin_amdgcn_mfma_f32_16x16x32_bf16(
                    a0[i], b0[j], acc[i][j], 0, 0, 0);
#pragma unroll
        for (int i = 0; i < 4; ++i)
#pragma unroll
            for (int j = 0; j < 4; ++j)
                acc[i][j] = __builtin_amdgcn_mfma_f32_16x16x32_bf16(
                    a1[i], b1[j], acc[i][j], 0, 0, 0);
        __builtin_amdgcn_s_setprio(0);
        cur ^= 1;
    }
#undef G2_STAGE

#pragma unroll
    for (int fi = 0; fi < 4; ++fi) {
#pragma unroll
        for (int j = 0; j < 4; ++j) {
            int col = bn * 128 + wc * 64 + j * 16 + r;
#pragma unroll
            for (int qq = 0; qq < 4; ++qq) {
                int row = bm * 128 + wr * 64 + fi * 16 + g * 4 + qq;
                size_t idx = (size_t)row * ODIM + col;
                float v = acc[fi][j][qq] + bout[col] + b2f(resb[idx]);
                outb[idx] = f2b(v);
            }
        }
    }
}

// ---- RMS norm row-wise (bf16 in, f32 out) ----------------------------------
__global__ __launch_bounds__(256) void k_rms(
    const ushort* __restrict__ outb, const float* __restrict__ lnw,
    float* __restrict__ out) {
    int row = blockIdx.x, t = threadIdx.x;
    const ushort* p = outb + (size_t)row * ODIM;
    float v0 = b2f(p[t]), v1 = b2f(p[t + 256]), v2 = b2f(p[t + 512]);
    float s = v0 * v0 + v1 * v1 + v2 * v2;
#pragma unroll
    for (int off = 32; off > 0; off >>= 1) s += __shfl_down(s, off, 64);
    __shared__ float ws4[4];
    if ((t & 63) == 0) ws4[t >> 6] = s;
    __syncthreads();
    float tot = ws4[0] + ws4[1] + ws4[2] + ws4[3];
    float sc = rsqrtf(tot * (1.f / 768.f) + 1e-6f);
    out[(size_t)row * ODIM + t]       = lnw[t]       * v0 * sc;
    out[(size_t)row * ODIM + t + 256] = lnw[t + 256] * v1 * sc;
    out[(size_t)row * ODIM + t + 512] = lnw[t + 512] * v2 * sc;
}

extern "C" void kernel_launch(void* const* d_in, const int* in_sizes, int n_in,
                              void* d_out, int out_size, void* d_ws, size_t ws_size,
                              hipStream_t stream) {
    const float* ew   = (const float*)d_in[2];
    const int*   ei   = (const int*)d_in[3];
    const float* xf   = (const float*)d_in[4];
    const float* Whid = (const float*)d_in[5];
    const float* bhid = (const float*)d_in[6];
    const float* Wout = (const float*)d_in[7];
    const float* bout = (const float*)d_in[8];
    const float* Wres = (const float*)d_in[9];
    const float* bres = (const float*)d_in[10];
    const float* lnw  = (const float*)d_in[11];

    char* ws = (char*)d_ws;
    ushort* Ap   = (ushort*)(ws);                    // 8192*704*2 = 11534336
    ushort* Bp   = (ushort*)(ws + 11534336);         // 1792*704*2 = 2523136
    ushort* Wb   = (ushort*)(ws + 14057472);         // 768*1024*2 = 1572864
    ushort* hidB = (ushort*)(ws + 15630336);         // 8192*1024*2 = 16777216
    ushort* resb = (ushort*)(ws + 32407552);         // 8192*768*2  = 12582912
    ushort* outb = (ushort*)(ws + 44990464);         // 8192*768*2  = 12582912

    k_pack<<<3816, 256, 0, stream>>>(ew, ei, xf, Whid, bhid, Wres, bres, Wout,
                                     Ap, Bp, Wb);
    k_gemm1<<<896, 256, 0, stream>>>(Ap, Bp, hidB, resb);
    k_gemm2<<<384, 256, 0, stream>>>(hidB, Wb, bout, resb, outb);
    k_rms<<<8192, 256, 0, stream>>>(outb, lnw, (float*)d_out);
}

// Round 18
// 67.163 us; speedup vs baseline: 1.0697x; 1.0044x over previous
//
#include <hip/hip_runtime.h>
#include <hip/hip_bf16.h>

#define TOKENS 8192
#define D_IN   256
#define HDIM   1024
#define ODIM   768
#define KPACK  704    // 640 statically-valid cols + bias chunk + pad -> 11 x BK=64
#define NCHUNK 88     // KPACK/8

typedef short bf16x8 __attribute__((ext_vector_type(8)));
typedef float f32x4  __attribute__((ext_vector_type(4)));

static __device__ __forceinline__ ushort f2b(float f) {
    union { __hip_bfloat16 b; ushort u; } cv;
    cv.b = __float2bfloat16(f);
    return cv.u;
}
static __device__ __forceinline__ float b2f(ushort u) {
    union { ushort u; __hip_bfloat16 b; } cv;
    cv.u = u;
    return __bfloat162float(cv.b);
}

// packed chunk index (0..79) -> (expert, source col d0); static masks:
// e0: cols [0,32)u[128,160) = 8 chunks; e1: 16; e2: 24; e3: 32 chunks
static __device__ __forceinline__ void chunk_map(int c8, int& e, int& d0) {
    int cc;
    if (c8 < 8)       { e = 0; cc = c8; }
    else if (c8 < 24) { e = 1; cc = c8 - 8; }
    else if (c8 < 48) { e = 2; cc = c8 - 24; }
    else              { e = 3; cc = c8 - 48; }
    int half = 4 * (e + 1);
    d0 = (cc < half) ? cc * 8 : 128 + (cc - half) * 8;
}

// direct global->LDS DMA, 16B/lane; LDS dest = wave-uniform base + lane*16
static __device__ __forceinline__ void stage16(const ushort* g, ushort* l) {
    __builtin_amdgcn_global_load_lds(
        (const __attribute__((address_space(1))) void*)g,
        (__attribute__((address_space(3))) void*)l, 16, 0, 0);
}

// tanh-form GELU (max dev from exact erf-GELU ~3e-4)
static __device__ __forceinline__ float gelu_f(float v) {
    float y = 0.7978845608f * v * (1.f + 0.044715f * v * v);
    return v - v / (__expf(2.f * y) + 1.f);
}

// ---- K0: fused packing: A'' (route inline) + B'' + W_out -------------------
#define A_ITEMS  (TOKENS * NCHUNK)            // 720896
#define B_ITEMS  (1792 * NCHUNK)              // 157696
#define W_ITEMS  (768 * 128)                  // 98304   -> total 976896 = 3816*256
__global__ __launch_bounds__(256) void k_pack(
    const float* __restrict__ ew, const int* __restrict__ ei,
    const float* __restrict__ xf,
    const float* __restrict__ Whid, const float* __restrict__ bhid,
    const float* __restrict__ Wres, const float* __restrict__ bres,
    const float* __restrict__ Wout,
    ushort* __restrict__ Ap, ushort* __restrict__ Bp, ushort* __restrict__ Wb) {
    int gid = blockIdx.x * 256 + threadIdx.x;
    if (gid < A_ITEMS) {
        int n  = gid / NCHUNK;
        int c8 = gid - n * NCHUNK;
        int   i0 = ei[2 * n], i1 = ei[2 * n + 1];
        float w0 = ew[2 * n], w1 = ew[2 * n + 1];
        bool v0 = (unsigned)i0 < 4u, v1 = (unsigned)i1 < 4u;
        float rs = (v0 ? w0 : 0.f) + (v1 ? w1 : 0.f);
        if (rs == 0.f) rs = 1.f;
        float o0 = v0 ? w0 / rs : 0.f;
        float o1 = v1 ? w1 / rs : 0.f;
        ushort o[8] __attribute__((aligned(16))) = {0, 0, 0, 0, 0, 0, 0, 0};
        if (c8 < 80) {
            int e, d0;
            chunk_map(c8, e, d0);
            float w = ((v0 && i0 == e) ? o0 : 0.f) + ((v1 && i1 == e) ? o1 : 0.f);
            if (w != 0.f) {
                const float* s = xf + ((size_t)e * TOKENS + n) * D_IN + d0;
#pragma unroll
                for (int j = 0; j < 8; ++j) {
                    float v = s[j];
                    if (!(v == v)) v = 0.f;   // nan_to_num
                    o[j] = f2b(w * v);
                }
            }
        } else if (c8 == 80) {
#pragma unroll
            for (int j = 0; j < 4; ++j) {
                float m = ((v0 && i0 == j) ? o0 : 0.f) + ((v1 && i1 == j) ? o1 : 0.f);
                o[j] = f2b(m);
            }
        }
        *(uint4*)(Ap + (size_t)n * KPACK + c8 * 8) = *(const uint4*)o;
    } else if (gid < A_ITEMS + B_ITEMS) {
        int g2 = gid - A_ITEMS;
        int o_ = g2 / NCHUNK;
        int c8 = g2 - o_ * NCHUNK;
        ushort v[8] __attribute__((aligned(16))) = {0, 0, 0, 0, 0, 0, 0, 0};
        if (c8 < 80) {
            int e, d0;
            chunk_map(c8, e, d0);
            const float* s = (o_ < HDIM)
                ? Whid + ((size_t)e * HDIM + o_) * D_IN + d0
                : Wres + ((size_t)e * ODIM + (o_ - HDIM)) * D_IN + d0;
#pragma unroll
            for (int j = 0; j < 8; ++j) v[j] = f2b(s[j]);
        } else if (c8 == 80) {
#pragma unroll
            for (int j = 0; j < 4; ++j) {
                float b = (o_ < HDIM) ? bhid[j * HDIM + o_] : bres[j * ODIM + (o_ - HDIM)];
                v[j] = f2b(b);
            }
        }
        *(uint4*)(Bp + (size_t)o_ * KPACK + c8 * 8) = *(const uint4*)v;
    } else {
        int g3 = gid - A_ITEMS - B_ITEMS;
        const float* s = Wout + (size_t)g3 * 8;
        ushort v[8] __attribute__((aligned(16)));
#pragma unroll
        for (int j = 0; j < 8; ++j) v[j] = f2b(s[j]);
        *(uint4*)(Wb + (size_t)g3 * 8) = *(const uint4*)v;
    }
}

// ---- GEMM1: exact R12 structure (128^2, BK=64, 2 blocks/CU, early staging) -
__global__ __launch_bounds__(256, 2) void k_gemm1(
    const ushort* __restrict__ A, const ushort* __restrict__ B,
    ushort* __restrict__ hidB, ushort* __restrict__ resb) {
    __shared__ __align__(16) ushort As[2][128 * 64];
    __shared__ __align__(16) ushort Bs[2][128 * 64];
    const int tid = threadIdx.x;
    const int lane = tid & 63, w = tid >> 6;
    const int wr = w >> 1, wc = w & 1;
    const int r = lane & 15, g = lane >> 4;
    const int sx = r & 7;

    // XCD-bijective swizzle: 896 blocks = 8 x 112; consecutive widx share bm
    int bid  = blockIdx.x;
    int widx = (bid & 7) * 112 + (bid >> 3);
    int bm = widx / 14, bn = widx - bm * 14;

    const int srow = tid >> 3;                  // 0..31
    const int gc   = (tid & 7) ^ (srow & 7);
    const ushort* Ag = A + (size_t)(bm * 128 + srow) * KPACK + gc * 8;
    const ushort* Bg = B + (size_t)(bn * 128 + srow) * KPACK + gc * 8;
    const int ldst = (w * 8) * 64;

#define G1_STAGE(p, kt) do {                                            \
    _Pragma("unroll")                                                   \
    for (int i_ = 0; i_ < 4; ++i_) {                                    \
        stage16(Ag + (size_t)(i_ * 32) * KPACK + (kt), &As[p][ldst + i_ * 32 * 64]); \
        stage16(Bg + (size_t)(i_ * 32) * KPACK + (kt), &Bs[p][ldst + i_ * 32 * 64]); \
    } } while (0)

    G1_STAGE(0, 0);
    G1_STAGE(1, 64);

    f32x4 acc[4][4] = {};
    const int cA = (wr * 64 + r) * 64;
    const int cB = (wc * 64 + r) * 64;
    const int cs0 = ((0 * 4 + g) ^ sx) * 8;
    const int cs1 = ((1 * 4 + g) ^ sx) * 8;

    int cur = 0;
#pragma unroll
    for (int t = 0; t < 11; ++t) {
        if (t < 10) asm volatile("s_waitcnt vmcnt(8)" ::: "memory");
        else        asm volatile("s_waitcnt vmcnt(0)" ::: "memory");
        __builtin_amdgcn_s_barrier();
        const ushort* Ab = As[cur];
        const ushort* Bb = Bs[cur];
        bf16x8 a0[4], b0[4], a1[4], b1[4];
#pragma unroll
        for (int j = 0; j < 4; ++j) {
            b0[j] = *(const bf16x8*)&Bb[cB + j * 16 * 64 + cs0];
            b1[j] = *(const bf16x8*)&Bb[cB + j * 16 * 64 + cs1];
        }
#pragma unroll
        for (int i = 0; i < 4; ++i) {
            a0[i] = *(const bf16x8*)&Ab[cA + i * 16 * 64 + cs0];
            a1[i] = *(const bf16x8*)&Ab[cA + i * 16 * 64 + cs1];
        }
        asm volatile("s_waitcnt lgkmcnt(0)" ::: "memory");
        __builtin_amdgcn_sched_barrier(0);
        __builtin_amdgcn_s_barrier();
        if (t + 2 < 11) G1_STAGE(cur, (t + 2) * 64);   // early issue under MFMA
        __builtin_amdgcn_s_setprio(1);
#pragma unroll
        for (int i = 0; i < 4; ++i)
#pragma unroll
            for (int j = 0; j < 4; ++j)
                acc[i][j] = __builtin_amdgcn_mfma_f32_16x16x32_bf16(
                    a0[i], b0[j], acc[i][j], 0, 0, 0);
#pragma unroll
        for (int i = 0; i < 4; ++i)
#pragma unroll
            for (int j = 0; j < 4; ++j)
                acc[i][j] = __builtin_amdgcn_mfma_f32_16x16x32_bf16(
                    a1[i], b1[j], acc[i][j], 0, 0, 0);
        __builtin_amdgcn_s_setprio(0);
        cur ^= 1;
    }
#undef G1_STAGE

    if (bn < 8) {   // hid block: GELU -> bf16
#pragma unroll
        for (int fi = 0; fi < 4; ++fi) {
#pragma unroll
            for (int j = 0; j < 4; ++j) {
                int col = bn * 128 + wc * 64 + j * 16 + r;
#pragma unroll
                for (int qq = 0; qq < 4; ++qq) {
                    int row = bm * 128 + wr * 64 + fi * 16 + g * 4 + qq;
                    hidB[(size_t)row * HDIM + col] = f2b(gelu_f(acc[fi][j][qq]));
                }
            }
        }
    } else {        // res block
#pragma unroll
        for (int fi = 0; fi < 4; ++fi) {
#pragma unroll
            for (int j = 0; j < 4; ++j) {
                int col = (bn - 8) * 128 + wc * 64 + j * 16 + r;
#pragma unroll
                for (int qq = 0; qq < 4; ++qq) {
                    int row = bm * 128 + wr * 64 + fi * 16 + g * 4 + qq;
                    resb[(size_t)row * ODIM + col] = f2b(acc[fi][j][qq]);
                }
            }
        }
    }
}

// ---- GEMM2: R12 loop + XCD-chunked bm-major grid (384 = 8 XCD x 48) --------
// Each XCD owns 8 consecutive bm panels -> its hidB slice (2MB) fits the 4MB
// per-XCD L2; Wb (1.5MB) is hot everywhere. A-panel reads become L2 hits.
__global__ __launch_bounds__(256, 2) void k_gemm2(
    const ushort* __restrict__ A, const ushort* __restrict__ B,
    const float* __restrict__ bout, const ushort* __restrict__ resb,
    ushort* __restrict__ outb) {
    __shared__ __align__(16) ushort As[2][128 * 64];
    __shared__ __align__(16) ushort Bs[2][128 * 64];
    const int tid = threadIdx.x;
    const int lane = tid & 63, w = tid >> 6;
    const int wr = w >> 1, wc = w & 1;
    const int r = lane & 15, g = lane >> 4;

    // bijective XCD swizzle: widx = xcd*48 + j; bm-major (bn fastest)
    int bid  = blockIdx.x;
    int widx = (bid & 7) * 48 + (bid >> 3);
    int bm = widx / 6, bn = widx - bm * 6;

    const int srow = tid >> 3;
    const int gc   = (tid & 7) ^ (srow & 7);
    const ushort* Ag = A + (size_t)(bm * 128 + srow) * HDIM + gc * 8;
    const ushort* Bg = B + (size_t)(bn * 128 + srow) * HDIM + gc * 8;
    const int ldst = (w * 8) * 64;

#define G2_STAGE(p, kt) do {                                            \
    _Pragma("unroll")                                                   \
    for (int i_ = 0; i_ < 4; ++i_) {                                    \
        stage16(Ag + (size_t)(i_ * 32) * HDIM + (kt), &As[p][ldst + i_ * 32 * 64]); \
        stage16(Bg + (size_t)(i_ * 32) * HDIM + (kt), &Bs[p][ldst + i_ * 32 * 64]); \
    } } while (0)

    G2_STAGE(0, 0);
    G2_STAGE(1, 64);

    f32x4 acc[4][4] = {};
    const int cA = (wr * 64 + r) * 64;
    const int cB = (wc * 64 + r) * 64;
    const int sx = r & 7;
    const int cs0 = ((0 * 4 + g) ^ sx) * 8;
    const int cs1 = ((1 * 4 + g) ^ sx) * 8;

    int cur = 0;
#pragma unroll
    for (int t = 0; t < 16; ++t) {
        if (t < 15) asm volatile("s_waitcnt vmcnt(8)" ::: "memory");
        else        asm volatile("s_waitcnt vmcnt(0)" ::: "memory");
        __builtin_amdgcn_s_barrier();
        const ushort* Ab = As[cur];
        const ushort* Bb = Bs[cur];
        bf16x8 a0[4], b0[4], a1[4], b1[4];
#pragma unroll
        for (int j = 0; j < 4; ++j) {
            b0[j] = *(const bf16x8*)&Bb[cB + j * 16 * 64 + cs0];
            b1[j] = *(const bf16x8*)&Bb[cB + j * 16 * 64 + cs1];
        }
#pragma unroll
        for (int i = 0; i < 4; ++i) {
            a0[i] = *(const bf16x8*)&Ab[cA + i * 16 * 64 + cs0];
            a1[i] = *(const bf16x8*)&Ab[cA + i * 16 * 64 + cs1];
        }
        asm volatile("s_waitcnt lgkmcnt(0)" ::: "memory");
        __builtin_amdgcn_sched_barrier(0);
        __builtin_amdgcn_s_barrier();
        if (t + 2 < 16) G2_STAGE(cur, (t + 2) * 64);   // early issue under MFMA
        __builtin_amdgcn_s_setprio(1);
#pragma unroll
        for (int i = 0; i < 4; ++i)
#pragma unroll
            for (int j = 0; j < 4; ++j)
                acc[i][j] = __builtin_amdgcn_mfma_f32_16x16x32_bf16(
                    a0[i], b0[j], acc[i][j], 0, 0, 0);
#pragma unroll
        for (int i = 0; i < 4; ++i)
#pragma unroll
            for (int j = 0; j < 4; ++j)
                acc[i][j] = __builtin_amdgcn_mfma_f32_16x16x32_bf16(
                    a1[i], b1[j], acc[i][j], 0, 0, 0);
        __builtin_amdgcn_s_setprio(0);
        cur ^= 1;
    }
#undef G2_STAGE

#pragma unroll
    for (int fi = 0; fi < 4; ++fi) {
#pragma unroll
        for (int j = 0; j < 4; ++j) {
            int col = bn * 128 + wc * 64 + j * 16 + r;
#pragma unroll
            for (int qq = 0; qq < 4; ++qq) {
                int row = bm * 128 + wr * 64 + fi * 16 + g * 4 + qq;
                size_t idx = (size_t)row * ODIM + col;
                float v = acc[fi][j][qq] + bout[col] + b2f(resb[idx]);
                outb[idx] = f2b(v);
            }
        }
    }
}

// ---- RMS norm row-wise (bf16 in, f32 out) ----------------------------------
__global__ __launch_bounds__(256) void k_rms(
    const ushort* __restrict__ outb, const float* __restrict__ lnw,
    float* __restrict__ out) {
    int row = blockIdx.x, t = threadIdx.x;
    const ushort* p = outb + (size_t)row * ODIM;
    float v0 = b2f(p[t]), v1 = b2f(p[t + 256]), v2 = b2f(p[t + 512]);
    float s = v0 * v0 + v1 * v1 + v2 * v2;
#pragma unroll
    for (int off = 32; off > 0; off >>= 1) s += __shfl_down(s, off, 64);
    __shared__ float ws4[4];
    if ((t & 63) == 0) ws4[t >> 6] = s;
    __syncthreads();
    float tot = ws4[0] + ws4[1] + ws4[2] + ws4[3];
    float sc = rsqrtf(tot * (1.f / 768.f) + 1e-6f);
    out[(size_t)row * ODIM + t]       = lnw[t]       * v0 * sc;
    out[(size_t)row * ODIM + t + 256] = lnw[t + 256] * v1 * sc;
    out[(size_t)row * ODIM + t + 512] = lnw[t + 512] * v2 * sc;
}

extern "C" void kernel_launch(void* const* d_in, const int* in_sizes, int n_in,
                              void* d_out, int out_size, void* d_ws, size_t ws_size,
                              hipStream_t stream) {
    const float* ew   = (const float*)d_in[2];
    const int*   ei   = (const int*)d_in[3];
    const float* xf   = (const float*)d_in[4];
    const float* Whid = (const float*)d_in[5];
    const float* bhid = (const float*)d_in[6];
    const float* Wout = (const float*)d_in[7];
    const float* bout = (const float*)d_in[8];
    const float* Wres = (const float*)d_in[9];
    const float* bres = (const float*)d_in[10];
    const float* lnw  = (const float*)d_in[11];

    char* ws = (char*)d_ws;
    ushort* Ap   = (ushort*)(ws);                    // 8192*704*2 = 11534336
    ushort* Bp   = (ushort*)(ws + 11534336);         // 1792*704*2 = 2523136
    ushort* Wb   = (ushort*)(ws + 14057472);         // 768*1024*2 = 1572864
    ushort* hidB = (ushort*)(ws + 15630336);         // 8192*1024*2 = 16777216
    ushort* resb = (ushort*)(ws + 32407552);         // 8192*768*2  = 12582912
    ushort* outb = (ushort*)(ws + 44990464);         // 8192*768*2  = 12582912

    k_pack<<<3816, 256, 0, stream>>>(ew, ei, xf, Whid, bhid, Wres, bres, Wout,
                                     Ap, Bp, Wb);
    k_gemm1<<<896, 256, 0, stream>>>(Ap, Bp, hidB, resb);
    k_gemm2<<<384, 256, 0, stream>>>(hidB, Wb, bout, resb, outb);
    k_rms<<<8192, 256, 0, stream>>>(outb, lnw, (float*)d_out);
}